// Round 1
// baseline (3678.391 us; speedup 1.0000x reference)
//
#include <hip/hip_runtime.h>

#define HW 128
#define C 256
#define SCALE 0.17677669529663687f  // 1/sqrt(32)

// LDS pool layout (float offsets):
//   xs     [64][256]            @ 0      (16384 floats)
//   wch    [96][64]  (f4-swz)   @ 16384  (6144)   -- aliased by ps[64][68] (4352)
//   qs     [64][32]  (f4-swz)   @ 22528  (2048)
//   ks     [64][32]  (f4-swz)   @ 24576  (2048)
//   vs     [64][32]  (f4-swz)   @ 26624  (2048)
//   ao     [64][32]  (f4-swz)   @ 28672  (2048)
//   wo     [256][32] (f4-swz)   @ 30720  (8192)
//   pe     [225]                @ 38912
// total = 39137 floats = 156548 B  (<= 160 KiB)

__global__ __launch_bounds__(512)
void winattn_kernel(const float* __restrict__ x, const float* __restrict__ wqkv,
                    const float* __restrict__ peg, const float* __restrict__ wout,
                    const float* __restrict__ bout, float* __restrict__ out)
{
    __shared__ __align__(16) float smem[39137];
    float* xs = smem;
    float* wch = smem + 16384;
    float* ps  = smem + 16384;   // alias of wch (safe: phases separated by barriers)
    float* qs  = smem + 22528;
    float* ks  = smem + 24576;
    float* vs  = smem + 26624;
    float* ao  = smem + 28672;
    float* wo  = smem + 30720;
    float* pe  = smem + 38912;

    const int tid = threadIdx.x;
    const int img = blockIdx.x >> 8;
    const int win = blockIdx.x & 255;
    const size_t base = ((size_t)(img * HW + (win >> 4) * 8) * HW + (win & 15) * 8) * C;

    if (tid < 225) pe[tid] = peg[tid];

    // stage x window: 64 tokens x 256 ch (4096 float4, coalesced)
    #pragma unroll
    for (int i = 0; i < 8; ++i) {
        int f = tid + i * 512;
        int t = f >> 6, c4 = f & 63;
        float4 v = reinterpret_cast<const float4*>(x + base + (size_t)((t >> 3) * HW + (t & 7)) * C)[c4];
        reinterpret_cast<float4*>(xs + t * 256)[c4] = v;
    }

    float facc[32];
    #pragma unroll
    for (int j = 0; j < 32; ++j) facc[j] = 0.f;

    const int r0   = tid & 31;   // qkv: output row within 32-block (== d)
    const int tg   = tid >> 5;   // qkv: token group 0..15 (4 tokens each)
    const int trow = tid >> 3;   // attn/proj: token 0..63
    const int p    = tid & 7;    // attn: j-phase / proj: o-phase

    __syncthreads();

    #pragma unroll 1
    for (int h = 0; h < 8; ++h) {
        // ---------------- QKV projection for head h ----------------
        float acc0[4] = {0.f,0.f,0.f,0.f};
        float acc1[4] = {0.f,0.f,0.f,0.f};
        float acc2[4] = {0.f,0.f,0.f,0.f};
        #pragma unroll 1
        for (int ch = 0; ch < 4; ++ch) {
            __syncthreads();  // protect wch (and its ps alias) from previous readers
            #pragma unroll
            for (int i = 0; i < 3; ++i) {
                int f = tid + i * 512;          // 0..1535
                int r = f >> 4, cc4 = f & 15;   // 96 rows x 16 float4
                float4 v = reinterpret_cast<const float4*>(
                    wqkv + (size_t)((r >> 5) * 256 + h * 32 + (r & 31)) * 256 + ch * 64)[cc4];
                reinterpret_cast<float4*>(wch + r * 64)[cc4 ^ (r & 15)] = v;
            }
            __syncthreads();
            #pragma unroll
            for (int c4 = 0; c4 < 16; ++c4) {
                const int sidx = c4 ^ (r0 & 15);
                float4 w0 = reinterpret_cast<const float4*>(wch + r0 * 64)[sidx];
                float4 w1 = reinterpret_cast<const float4*>(wch + (r0 + 32) * 64)[sidx];
                float4 w2 = reinterpret_cast<const float4*>(wch + (r0 + 64) * 64)[sidx];
                #pragma unroll
                for (int tt = 0; tt < 4; ++tt) {
                    float4 xv = reinterpret_cast<const float4*>(xs + (tg * 4 + tt) * 256)[ch * 16 + c4];
                    acc0[tt] += w0.x*xv.x + w0.y*xv.y + w0.z*xv.z + w0.w*xv.w;
                    acc1[tt] += w1.x*xv.x + w1.y*xv.y + w1.z*xv.z + w1.w*xv.w;
                    acc2[tt] += w2.x*xv.x + w2.y*xv.y + w2.z*xv.z + w2.w*xv.w;
                }
            }
        }
        // write q (pre-scaled), k, v into swizzled [64][32] tiles
        #pragma unroll
        for (int tt = 0; tt < 4; ++tt) {
            int t = tg * 4 + tt;
            int col = (((r0 >> 2) ^ (t & 7)) << 2) + (r0 & 3);
            qs[t * 32 + col] = acc0[tt] * SCALE;
            ks[t * 32 + col] = acc1[tt];
            vs[t * 32 + col] = acc2[tt];
        }
        __syncthreads();

        // ---------------- scores + softmax (8 lanes per row) ----------------
        float4 qv[8];
        #pragma unroll
        for (int d4 = 0; d4 < 8; ++d4)
            qv[d4] = reinterpret_cast<const float4*>(qs + trow * 32)[d4 ^ (trow & 7)];
        float s[8];
        #pragma unroll
        for (int jj = 0; jj < 8; ++jj) {
            int j = p + jj * 8;
            float d = 0.f;
            #pragma unroll
            for (int d4 = 0; d4 < 8; ++d4) {
                float4 kv = reinterpret_cast<const float4*>(ks + j * 32)[d4 ^ (j & 7)];
                d += qv[d4].x*kv.x + qv[d4].y*kv.y + qv[d4].z*kv.z + qv[d4].w*kv.w;
            }
            // bias: rel = idx[j] - idx[i] + 7
            int dr = (j >> 3) - (trow >> 3) + 7;
            int dc = (j & 7) - (trow & 7) + 7;
            s[jj] = d + pe[dr * 15 + dc];
        }
        float m = s[0];
        #pragma unroll
        for (int jj = 1; jj < 8; ++jj) m = fmaxf(m, s[jj]);
        m = fmaxf(m, __shfl_xor(m, 1));
        m = fmaxf(m, __shfl_xor(m, 2));
        m = fmaxf(m, __shfl_xor(m, 4));
        float sum = 0.f;
        #pragma unroll
        for (int jj = 0; jj < 8; ++jj) { s[jj] = __expf(s[jj] - m); sum += s[jj]; }
        sum += __shfl_xor(sum, 1);
        sum += __shfl_xor(sum, 2);
        sum += __shfl_xor(sum, 4);
        float inv = 1.f / sum;
        #pragma unroll
        for (int jj = 0; jj < 8; ++jj)
            ps[trow * 68 + p + jj * 8] = s[jj] * inv;
        __syncthreads();

        // ---------------- PV: ao[trow][4p..4p+3] ----------------
        float4 po = make_float4(0.f, 0.f, 0.f, 0.f);
        #pragma unroll
        for (int j4 = 0; j4 < 16; ++j4) {
            float4 pp = reinterpret_cast<const float4*>(ps + trow * 68)[j4];
            float pj[4] = {pp.x, pp.y, pp.z, pp.w};
            #pragma unroll
            for (int e = 0; e < 4; ++e) {
                int j = j4 * 4 + e;
                float4 vv = reinterpret_cast<const float4*>(vs + j * 32)[p ^ (j & 7)];
                po.x += pj[e]*vv.x; po.y += pj[e]*vv.y; po.z += pj[e]*vv.z; po.w += pj[e]*vv.w;
            }
        }
        reinterpret_cast<float4*>(ao + trow * 32)[p ^ (trow & 7)] = po;

        // stage w_out slice [:, h*32 : h*32+32] (swizzled)
        #pragma unroll
        for (int i = 0; i < 4; ++i) {
            int f = tid + i * 512;         // 0..2047
            int o = f >> 3, d4 = f & 7;
            float4 v = reinterpret_cast<const float4*>(wout + (size_t)o * 256 + h * 32)[d4];
            reinterpret_cast<float4*>(wo + o * 32)[d4 ^ (o & 7)] = v;
        }
        __syncthreads();

        // ---------------- projection accumulate (o = p + 8j) ----------------
        #pragma unroll
        for (int d4 = 0; d4 < 8; ++d4) {
            float4 av = reinterpret_cast<const float4*>(ao + trow * 32)[d4 ^ (trow & 7)];
            #pragma unroll
            for (int j = 0; j < 32; ++j) {
                int o = p + 8 * j;
                float4 wv = reinterpret_cast<const float4*>(wo + o * 32)[d4 ^ p];
                facc[j] += av.x*wv.x + av.y*wv.y + av.z*wv.z + av.w*wv.w;
            }
        }
    }

    // ---------------- write output ----------------
    {
        float* op = out + base + (size_t)((trow >> 3) * HW + (trow & 7)) * C;
        #pragma unroll
        for (int j = 0; j < 32; ++j) {
            int o = p + 8 * j;
            op[o] = facc[j] + bout[o];
        }
    }
}

extern "C" void kernel_launch(void* const* d_in, const int* in_sizes, int n_in,
                              void* d_out, int out_size, void* d_ws, size_t ws_size,
                              hipStream_t stream) {
    const float* x     = (const float*)d_in[0];
    const float* wqkv  = (const float*)d_in[1];
    const float* peg   = (const float*)d_in[2];
    const float* wout  = (const float*)d_in[3];
    const float* bout  = (const float*)d_in[4];
    float* out = (float*)d_out;
    hipLaunchKernelGGL(winattn_kernel, dim3(2048), dim3(512), 0, stream,
                       x, wqkv, peg, wout, bout, out);
}

// Round 2
// 382.802 us; speedup vs baseline: 9.6091x; 9.6091x over previous
//
#include <hip/hip_runtime.h>

// Swin-style window attention, MI355X gfx950.
// Per block = one 8x8 window (64 tokens, C=256). 512 threads = 8 waves; wave w owns head w.
// All GEMMs on MFMA 16x16x32 bf16; QKV projection uses hi/lo bf16 split (3-product) for fp32-level accuracy.
// LDS (112 KB): phase A: xh[64][256]bf16 @0 (32K), xl @32768 (32K)  [GEMM1 operands]
//               phase B (after barrier, reuses 0..98304): per-wave 12K slices: q@0,k@4096,v_t@8192; P overlays k; ao overlays q
//               bias[64][64]f32 @98304 (16K)  [lives whole kernel]

typedef __attribute__((ext_vector_type(8))) short bf16x8;
typedef __attribute__((ext_vector_type(4))) float f32x4;

#define MFMA16(a,b,c) __builtin_amdgcn_mfma_f32_16x16x32_bf16(a,b,c,0,0,0)
#define SCALE 0.17677669529663687f

__device__ __forceinline__ short bfr(float f) {          // f32 -> bf16 bits (RNE)
    unsigned u = __builtin_bit_cast(unsigned, f);
    u = (u + 0x7FFFu + ((u >> 16) & 1u)) >> 16;
    return (short)u;
}
__device__ __forceinline__ float bft(short s) {          // bf16 bits -> f32
    unsigned u = ((unsigned)(unsigned short)s) << 16;
    return __builtin_bit_cast(float, u);
}

__global__ __launch_bounds__(512, 2)
void winattn_kernel(const float* __restrict__ x, const float* __restrict__ wqkv,
                    const float* __restrict__ peg, const float* __restrict__ wout,
                    const float* __restrict__ bout, float* __restrict__ out)
{
    __shared__ __align__(16) char lds[114688];
    const int tid = threadIdx.x;
    const int wave = tid >> 6, lane = tid & 63;
    const int lg = lane >> 4, ln = lane & 15;
    const int img = blockIdx.x >> 8, win = blockIdx.x & 255;
    const size_t base = ((size_t)(img * 128 + (win >> 4) * 8) * 128 + (win & 15) * 8) * 256;

    // ---------- Phase 0: stage x window as bf16 hi/lo (swizzled) + build bias matrix ----------
    #pragma unroll
    for (int i = 0; i < 4; ++i) {
        int ch = tid + i * 512;            // 2048 chunks of 8 floats
        int t = ch >> 5, cc = ch & 31;
        const float* gp = x + base + (size_t)(((t >> 3) * 128 + (t & 7)) * 256 + cc * 8);
        float4 f0 = *reinterpret_cast<const float4*>(gp);
        float4 f1 = *reinterpret_cast<const float4*>(gp + 4);
        float fv[8] = {f0.x,f0.y,f0.z,f0.w,f1.x,f1.y,f1.z,f1.w};
        bf16x8 hv, lv;
        #pragma unroll
        for (int j = 0; j < 8; ++j) {
            short h = bfr(fv[j]);
            hv[j] = h;
            lv[j] = bfr(fv[j] - bft(h));
        }
        int byt = (t * 512 + cc * 16) ^ ((t & 7) << 4);
        *reinterpret_cast<bf16x8*>(lds + byt) = hv;
        *reinterpret_cast<bf16x8*>(lds + 32768 + byt) = lv;
    }
    {
        float* bias = (float*)(lds + 98304);
        #pragma unroll
        for (int i = 0; i < 8; ++i) {
            int id = tid + i * 512;
            int bi = id >> 6, bj = id & 63;
            int dr = (bj >> 3) - (bi >> 3) + 7;
            int dc = (bj & 7) - (bi & 7) + 7;
            bias[id] = peg[dr * 15 + dc];
        }
    }
    __syncthreads();

    // ---------- Phase 1: GEMM1  qkv[64][96(head slice)] = X[64][256] @ Wqkv^T  (hi/lo, 3-product) ----------
    // wave w columns: o = tau*256 + w*32 + u*16 + ln  (tau = q/k/v, u = half)
    f32x4 acc[4][6];
    #pragma unroll
    for (int a = 0; a < 4; ++a)
        #pragma unroll
        for (int b = 0; b < 6; ++b) acc[a][b] = (f32x4){0.f,0.f,0.f,0.f};

    #pragma unroll 1
    for (int kk = 0; kk < 8; ++kk) {
        bf16x8 ah[4], al[4];
        #pragma unroll
        for (int mt = 0; mt < 4; ++mt) {
            int m = mt * 16 + ln;
            int byt = (m * 512 + kk * 64 + lg * 16) ^ ((m & 7) << 4);
            ah[mt] = *reinterpret_cast<const bf16x8*>(lds + byt);
            al[mt] = *reinterpret_cast<const bf16x8*>(lds + 32768 + byt);
        }
        bf16x8 bh[6], bl[6];
        #pragma unroll
        for (int nv = 0; nv < 6; ++nv) {
            int tau = nv >> 1, u = nv & 1;
            int o = tau * 256 + wave * 32 + u * 16 + ln;
            const float* gp = wqkv + (size_t)o * 256 + kk * 32 + lg * 8;
            float4 f0 = *reinterpret_cast<const float4*>(gp);
            float4 f1 = *reinterpret_cast<const float4*>(gp + 4);
            float fv[8] = {f0.x,f0.y,f0.z,f0.w,f1.x,f1.y,f1.z,f1.w};
            #pragma unroll
            for (int j = 0; j < 8; ++j) {
                short h = bfr(fv[j]);
                bh[nv][j] = h;
                bl[nv][j] = bfr(fv[j] - bft(h));
            }
        }
        #pragma unroll
        for (int mt = 0; mt < 4; ++mt)
            #pragma unroll
            for (int nv = 0; nv < 6; ++nv) {
                acc[mt][nv] = MFMA16(ah[mt], bh[nv], acc[mt][nv]);
                acc[mt][nv] = MFMA16(ah[mt], bl[nv], acc[mt][nv]);
                acc[mt][nv] = MFMA16(al[mt], bh[nv], acc[mt][nv]);
            }
    }
    __syncthreads();   // x dead; per-wave slice region becomes live

    // ---------- Phase 2: scatter q,k,v (bf16) into this wave's slice ----------
    char* slc = lds + wave * 12288;
    #pragma unroll
    for (int mt = 0; mt < 4; ++mt)
        #pragma unroll
        for (int u = 0; u < 2; ++u)
            #pragma unroll
            for (int r = 0; r < 4; ++r) {
                int t = mt * 16 + lg * 4 + r;
                int d = u * 16 + ln;
                int qb = (t * 64 + d * 2) ^ ((t & 3) << 4);
                *reinterpret_cast<short*>(slc + qb)        = bfr(acc[mt][u][r]);       // q
                *reinterpret_cast<short*>(slc + 4096 + qb) = bfr(acc[mt][2 + u][r]);   // k
            }
    // v transposed [d][t] with packed 4-token 8B writes
    #pragma unroll
    for (int mt = 0; mt < 4; ++mt)
        #pragma unroll
        for (int u = 0; u < 2; ++u) {
            int d = u * 16 + ln;
            int t0 = mt * 16 + lg * 4;
            unsigned w0 = (unsigned)(unsigned short)bfr(acc[mt][4 + u][0])
                        | ((unsigned)(unsigned short)bfr(acc[mt][4 + u][1]) << 16);
            unsigned w1 = (unsigned)(unsigned short)bfr(acc[mt][4 + u][2])
                        | ((unsigned)(unsigned short)bfr(acc[mt][4 + u][3]) << 16);
            int vb = (d * 128 + t0 * 2) ^ ((d & 7) << 4);
            *reinterpret_cast<uint2*>(slc + 8192 + vb) = make_uint2(w0, w1);
        }

    // ---------- Phase 3: QK^T + softmax + PV (head == wave) ----------
    bf16x8 aq[4], bk[4];
    #pragma unroll
    for (int mi = 0; mi < 4; ++mi) {
        int m = mi * 16 + ln;
        aq[mi] = *reinterpret_cast<const bf16x8*>(slc + ((m * 64 + lg * 16) ^ ((m & 3) << 4)));
    }
    #pragma unroll
    for (int nj = 0; nj < 4; ++nj) {
        int j = nj * 16 + ln;
        bk[nj] = *reinterpret_cast<const bf16x8*>(slc + 4096 + ((j * 64 + lg * 16) ^ ((j & 3) << 4)));
    }
    f32x4 sc[4][4];
    #pragma unroll
    for (int mi = 0; mi < 4; ++mi)
        #pragma unroll
        for (int nj = 0; nj < 4; ++nj)
            sc[mi][nj] = MFMA16(aq[mi], bk[nj], ((f32x4){0.f,0.f,0.f,0.f}));

    {
        const float* bias = (const float*)(lds + 98304);
        #pragma unroll
        for (int mi = 0; mi < 4; ++mi)
            #pragma unroll
            for (int nj = 0; nj < 4; ++nj)
                #pragma unroll
                for (int r = 0; r < 4; ++r) {
                    int m = mi * 16 + lg * 4 + r;
                    int n = nj * 16 + ln;
                    sc[mi][nj][r] = sc[mi][nj][r] * SCALE + bias[m * 64 + n];
                }
    }
    float pinv[4][4];
    #pragma unroll
    for (int mi = 0; mi < 4; ++mi)
        #pragma unroll
        for (int r = 0; r < 4; ++r) {
            float mx = fmaxf(fmaxf(sc[mi][0][r], sc[mi][1][r]), fmaxf(sc[mi][2][r], sc[mi][3][r]));
            mx = fmaxf(mx, __shfl_xor(mx, 1));
            mx = fmaxf(mx, __shfl_xor(mx, 2));
            mx = fmaxf(mx, __shfl_xor(mx, 4));
            mx = fmaxf(mx, __shfl_xor(mx, 8));
            float sum = 0.f;
            #pragma unroll
            for (int nj = 0; nj < 4; ++nj) {
                sc[mi][nj][r] = __expf(sc[mi][nj][r] - mx);
                sum += sc[mi][nj][r];
            }
            sum += __shfl_xor(sum, 1);
            sum += __shfl_xor(sum, 2);
            sum += __shfl_xor(sum, 4);
            sum += __shfl_xor(sum, 8);
            pinv[mi][r] = 1.f / sum;
        }

    f32x4 po[4][2];
    #pragma unroll
    for (int mi = 0; mi < 4; ++mi)
        #pragma unroll
        for (int u = 0; u < 2; ++u) po[mi][u] = (f32x4){0.f,0.f,0.f,0.f};

    #pragma unroll
    for (int kkv = 0; kkv < 2; ++kkv) {
        // stage P-half kkv (overlays k; safe: k already consumed, ordering via may-alias + in-order DS)
        #pragma unroll
        for (int half = 0; half < 2; ++half) {
            int nj = kkv * 2 + half;
            #pragma unroll
            for (int mi = 0; mi < 4; ++mi)
                #pragma unroll
                for (int r = 0; r < 4; ++r) {
                    int i = mi * 16 + lg * 4 + r;
                    int jj = half * 16 + ln;
                    *reinterpret_cast<short*>(slc + 4096 + ((i * 64 + jj * 2) ^ ((i & 3) << 4)))
                        = bfr(sc[mi][nj][r] * pinv[mi][r]);
                }
        }
        bf16x8 ap[4], bv[2];
        #pragma unroll
        for (int mi = 0; mi < 4; ++mi) {
            int m = mi * 16 + ln;
            ap[mi] = *reinterpret_cast<const bf16x8*>(slc + 4096 + ((m * 64 + lg * 16) ^ ((m & 3) << 4)));
        }
        #pragma unroll
        for (int u = 0; u < 2; ++u) {
            int d = u * 16 + ln;
            bv[u] = *reinterpret_cast<const bf16x8*>(slc + 8192 + ((d * 128 + kkv * 64 + lg * 16) ^ ((d & 7) << 4)));
        }
        #pragma unroll
        for (int mi = 0; mi < 4; ++mi)
            #pragma unroll
            for (int u = 0; u < 2; ++u)
                po[mi][u] = MFMA16(ap[mi], bv[u], po[mi][u]);
    }

    // stage attn_out (bf16) into slice (overlays q)
    #pragma unroll
    for (int mi = 0; mi < 4; ++mi)
        #pragma unroll
        for (int u = 0; u < 2; ++u)
            #pragma unroll
            for (int r = 0; r < 4; ++r) {
                int t = mi * 16 + lg * 4 + r;
                int d = u * 16 + ln;
                *reinterpret_cast<short*>(slc + ((t * 64 + d * 2) ^ ((t & 3) << 4))) = bfr(po[mi][u][r]);
            }
    __syncthreads();   // all waves' attn_out visible

    // ---------- Phase 4: out-proj  out[64][32 cols of this wave] = AO[64][256] @ Wout^T + b ----------
    f32x4 fo[4][2];
    #pragma unroll
    for (int mi = 0; mi < 4; ++mi)
        #pragma unroll
        for (int u = 0; u < 2; ++u) fo[mi][u] = (f32x4){0.f,0.f,0.f,0.f};
    float bo0 = bout[wave * 32 + ln];
    float bo1 = bout[wave * 32 + 16 + ln];

    #pragma unroll 1
    for (int hh = 0; hh < 8; ++hh) {
        const char* ahh = lds + hh * 12288;   // head hh's attn_out slice
        bf16x8 aa[4];
        #pragma unroll
        for (int mi = 0; mi < 4; ++mi) {
            int t = mi * 16 + ln;
            aa[mi] = *reinterpret_cast<const bf16x8*>(ahh + ((t * 64 + lg * 16) ^ ((t & 3) << 4)));
        }
        bf16x8 bb[2];
        #pragma unroll
        for (int u = 0; u < 2; ++u) {
            int oc = wave * 32 + u * 16 + ln;
            const float* gp = wout + (size_t)oc * 256 + hh * 32 + lg * 8;
            float4 f0 = *reinterpret_cast<const float4*>(gp);
            float4 f1 = *reinterpret_cast<const float4*>(gp + 4);
            float fv[8] = {f0.x,f0.y,f0.z,f0.w,f1.x,f1.y,f1.z,f1.w};
            #pragma unroll
            for (int j = 0; j < 8; ++j) bb[u][j] = bfr(fv[j]);
        }
        #pragma unroll
        for (int mi = 0; mi < 4; ++mi)
            #pragma unroll
            for (int u = 0; u < 2; ++u)
                fo[mi][u] = MFMA16(aa[mi], bb[u], fo[mi][u]);
    }

    #pragma unroll
    for (int mi = 0; mi < 4; ++mi)
        #pragma unroll
        for (int r = 0; r < 4; ++r) {
            int t = mi * 16 + lg * 4 + r;
            float* op = out + base + (size_t)(((t >> 3) * 128 + (t & 7)) * 256);
            op[wave * 32 + ln]      = fo[mi][0][r] + bo0;
            op[wave * 32 + 16 + ln] = fo[mi][1][r] + bo1;
        }
}

extern "C" void kernel_launch(void* const* d_in, const int* in_sizes, int n_in,
                              void* d_out, int out_size, void* d_ws, size_t ws_size,
                              hipStream_t stream) {
    const float* x    = (const float*)d_in[0];
    const float* wqkv = (const float*)d_in[1];
    const float* peg  = (const float*)d_in[2];
    const float* wout = (const float*)d_in[3];
    const float* bout = (const float*)d_in[4];
    float* out = (float*)d_out;
    hipLaunchKernelGGL(winattn_kernel, dim3(2048), dim3(512), 0, stream,
                       x, wqkv, peg, wout, bout, out);
}

// Round 3
// 160.771 us; speedup vs baseline: 22.8796x; 2.3810x over previous
//
#include <hip/hip_runtime.h>

// Swin window attention, MI355X gfx950. Block = one 8x8 window; 512 thr = 8 waves; wave w owns head w.
// All GEMMs bf16 MFMA 16x16x32. Weights pre-converted to bf16 fragments in d_ws by prologue kernel.
// LDS 65 KB: [0,32768) x window bf16 (GEMM1 A); after barrier [0,65536) = 8 x 8KB per-wave slices:
//   q@0 (4K, overlaid by v_t after aq loaded), k@4096 (overlaid by P, then ao). peg[225] f32 @65536.

typedef __attribute__((ext_vector_type(8))) short bf16x8;
typedef __attribute__((ext_vector_type(4))) float f32x4;

#define MFMA16(a,b,c) __builtin_amdgcn_mfma_f32_16x16x32_bf16(a,b,c,0,0,0)
#define SCALE 0.17677669529663687f
#define WS_QKV_BYTES 393216
#define WS_TOTAL_BYTES 524288

__device__ __forceinline__ short bfr(float f) {          // f32 -> bf16 bits (RNE)
    unsigned u = __builtin_bit_cast(unsigned, f);
    u = (u + 0x7FFFu + ((u >> 16) & 1u)) >> 16;
    return (short)u;
}

__device__ __forceinline__ bf16x8 cvt8(const float* gp) {
    float4 f0 = *reinterpret_cast<const float4*>(gp);
    float4 f1 = *reinterpret_cast<const float4*>(gp + 4);
    float fv[8] = {f0.x,f0.y,f0.z,f0.w,f1.x,f1.y,f1.z,f1.w};
    bf16x8 r;
    #pragma unroll
    for (int j = 0; j < 8; ++j) r[j] = bfr(fv[j]);
    return r;
}

// Pre-fragment weights to bf16. Fragment addressing: frag f = oblk*8 + kk holds 1 KB:
// lane (lg,ln) 16B at f*1024 + (lg*16+ln)*16, element (o = oblk*16+ln, k = kk*32+lg*8+e).
__global__ void prep_kernel(const float* __restrict__ wqkv, const float* __restrict__ wout,
                            char* __restrict__ ws) {
    int t = blockIdx.x * 256 + threadIdx.x;      // 32768 threads, 8 elems each
    const float* src;
    int byt;
    if (t < 24576) {                              // wqkv: 768 x 256
        int o = t >> 5, kc = t & 31;
        src = wqkv + o * 256 + kc * 8;
        byt = ((o >> 4) * 8 + (kc >> 2)) * 1024 + ((kc & 3) * 16 + (o & 15)) * 16;
    } else {                                      // wout: 256 x 256
        int t2 = t - 24576;
        int o = t2 >> 5, kc = t2 & 31;
        src = wout + o * 256 + kc * 8;
        byt = WS_QKV_BYTES + ((o >> 4) * 8 + (kc >> 2)) * 1024 + ((kc & 3) * 16 + (o & 15)) * 16;
    }
    *reinterpret_cast<bf16x8*>(ws + byt) = cvt8(src);
}

template<bool USE_WS>
__global__ __launch_bounds__(512, 4)
void winattn_kernel(const float* __restrict__ x, const float* __restrict__ wqkv,
                    const float* __restrict__ peg, const float* __restrict__ wout,
                    const float* __restrict__ bout, float* __restrict__ out,
                    const char* __restrict__ wsb)
{
    __shared__ __align__(16) char lds[66560];
    float* peg_lds = (float*)(lds + 65536);
    const int tid = threadIdx.x;
    const int wave = tid >> 6, lane = tid & 63;
    const int lg = lane >> 4, ln = lane & 15;
    const int img = blockIdx.x >> 8, win = blockIdx.x & 255;
    const size_t base = ((size_t)(img * 128 + (win >> 4) * 8) * 128 + (win & 15) * 8) * 256;

    // ---------- Phase 0: stage x window bf16 (swizzled) + peg ----------
    #pragma unroll
    for (int i = 0; i < 4; ++i) {
        int ch = tid + i * 512;                    // 2048 chunks of 8 floats
        int t = ch >> 5, cc = ch & 31;
        const float* gp = x + base + (size_t)(((t >> 3) * 128 + (t & 7)) * 256 + cc * 8);
        *reinterpret_cast<bf16x8*>(lds + ((t * 512 + cc * 16) ^ ((t & 7) << 4))) = cvt8(gp);
    }
    if (tid < 225) peg_lds[tid] = peg[tid];
    __syncthreads();

    // ---------- GEMM1: qkv head-slice [64][96] = X[64][256] @ Wqkv^T (single-product bf16) ----------
    f32x4 acc[4][6];
    #pragma unroll
    for (int a = 0; a < 4; ++a)
        #pragma unroll
        for (int b = 0; b < 6; ++b) acc[a][b] = (f32x4){0.f,0.f,0.f,0.f};

    const int lswz = (ln & 7) << 4;
    const int fl = (lg * 16 + ln) * 16;
    #pragma unroll 1
    for (int kk = 0; kk < 8; ++kk) {
        bf16x8 ah[4];
        #pragma unroll
        for (int mt = 0; mt < 4; ++mt)
            ah[mt] = *reinterpret_cast<const bf16x8*>(
                lds + (((mt * 16 + ln) * 512 + kk * 64 + lg * 16) ^ lswz));
        #pragma unroll
        for (int nv = 0; nv < 6; ++nv) {
            bf16x8 bh;
            if constexpr (USE_WS) {
                bh = *reinterpret_cast<const bf16x8*>(
                    wsb + (((nv >> 1) * 16 + wave * 2 + (nv & 1)) * 8 + kk) * 1024 + fl);
            } else {
                int o = (nv >> 1) * 256 + wave * 32 + (nv & 1) * 16 + ln;
                bh = cvt8(wqkv + (size_t)o * 256 + kk * 32 + lg * 8);
            }
            #pragma unroll
            for (int mt = 0; mt < 4; ++mt)
                acc[mt][nv] = MFMA16(ah[mt], bh, acc[mt][nv]);
        }
    }
    __syncthreads();   // x dead; slice region live

    // ---------- Phase 2: write q,k bf16 into wave slice (v stays in regs) ----------
    char* slc = lds + wave * 8192;
    #pragma unroll
    for (int mt = 0; mt < 4; ++mt)
        #pragma unroll
        for (int u = 0; u < 2; ++u)
            #pragma unroll
            for (int r = 0; r < 4; ++r) {
                int t = mt * 16 + lg * 4 + r;
                int d = u * 16 + ln;
                int qb = (t * 64 + d * 2) ^ ((t & 3) << 4);
                *reinterpret_cast<short*>(slc + qb)        = bfr(acc[mt][u][r]);       // q
                *reinterpret_cast<short*>(slc + 4096 + qb) = bfr(acc[mt][2 + u][r]);   // k
            }

    // ---------- Phase 3: QK^T + softmax + PV (head == wave) ----------
    bf16x8 aq[4], bk[4];
    #pragma unroll
    for (int mi = 0; mi < 4; ++mi) {
        int m = mi * 16 + ln;
        aq[mi] = *reinterpret_cast<const bf16x8*>(slc + ((m * 64 + lg * 16) ^ ((m & 3) << 4)));
    }
    #pragma unroll
    for (int nj = 0; nj < 4; ++nj) {
        int j = nj * 16 + ln;
        bk[nj] = *reinterpret_cast<const bf16x8*>(slc + 4096 + ((j * 64 + lg * 16) ^ ((j & 3) << 4)));
    }
    // v transposed [d][t] into q region (q fully consumed into aq; same-wave DS is in-order)
    #pragma unroll
    for (int mt = 0; mt < 4; ++mt)
        #pragma unroll
        for (int u = 0; u < 2; ++u) {
            int d = u * 16 + ln;
            int t0 = mt * 16 + lg * 4;
            unsigned w0 = (unsigned)(unsigned short)bfr(acc[mt][4 + u][0])
                        | ((unsigned)(unsigned short)bfr(acc[mt][4 + u][1]) << 16);
            unsigned w1 = (unsigned)(unsigned short)bfr(acc[mt][4 + u][2])
                        | ((unsigned)(unsigned short)bfr(acc[mt][4 + u][3]) << 16);
            int vb = (d * 128 + t0 * 2) ^ ((d & 7) << 4);
            *reinterpret_cast<uint2*>(slc + vb) = make_uint2(w0, w1);
        }

    f32x4 sc[4][4];
    #pragma unroll
    for (int mi = 0; mi < 4; ++mi)
        #pragma unroll
        for (int nj = 0; nj < 4; ++nj)
            sc[mi][nj] = MFMA16(aq[mi], bk[nj], ((f32x4){0.f,0.f,0.f,0.f}));

    // scale + relative-position bias (gathered from peg)
    #pragma unroll
    for (int mi = 0; mi < 4; ++mi)
        #pragma unroll
        for (int r = 0; r < 4; ++r) {
            int m = mi * 16 + lg * 4 + r;
            int mr = m >> 3, mc = m & 7;
            #pragma unroll
            for (int nj = 0; nj < 4; ++nj) {
                int n = nj * 16 + ln;
                int idx = ((n >> 3) - mr + 7) * 15 + ((n & 7) - mc + 7);
                sc[mi][nj][r] = fmaf(sc[mi][nj][r], SCALE, peg_lds[idx]);
            }
        }

    float pinv[4][4];
    #pragma unroll
    for (int mi = 0; mi < 4; ++mi)
        #pragma unroll
        for (int r = 0; r < 4; ++r) {
            float mx = fmaxf(fmaxf(sc[mi][0][r], sc[mi][1][r]), fmaxf(sc[mi][2][r], sc[mi][3][r]));
            mx = fmaxf(mx, __shfl_xor(mx, 1));
            mx = fmaxf(mx, __shfl_xor(mx, 2));
            mx = fmaxf(mx, __shfl_xor(mx, 4));
            mx = fmaxf(mx, __shfl_xor(mx, 8));
            float sum = 0.f;
            #pragma unroll
            for (int nj = 0; nj < 4; ++nj) {
                sc[mi][nj][r] = __expf(sc[mi][nj][r] - mx);
                sum += sc[mi][nj][r];
            }
            sum += __shfl_xor(sum, 1);
            sum += __shfl_xor(sum, 2);
            sum += __shfl_xor(sum, 4);
            sum += __shfl_xor(sum, 8);
            pinv[mi][r] = 1.f / sum;
        }

    f32x4 po[4][2];
    #pragma unroll
    for (int mi = 0; mi < 4; ++mi)
        #pragma unroll
        for (int u = 0; u < 2; ++u) po[mi][u] = (f32x4){0.f,0.f,0.f,0.f};

    #pragma unroll
    for (int kkv = 0; kkv < 2; ++kkv) {
        #pragma unroll
        for (int half = 0; half < 2; ++half) {       // P half into k region (k consumed)
            int nj = kkv * 2 + half;
            #pragma unroll
            for (int mi = 0; mi < 4; ++mi)
                #pragma unroll
                for (int r = 0; r < 4; ++r) {
                    int i = mi * 16 + lg * 4 + r;
                    int jj = half * 16 + ln;
                    *reinterpret_cast<short*>(slc + 4096 + ((i * 64 + jj * 2) ^ ((i & 3) << 4)))
                        = bfr(sc[mi][nj][r] * pinv[mi][r]);
                }
        }
        bf16x8 ap[4], bv[2];
        #pragma unroll
        for (int mi = 0; mi < 4; ++mi) {
            int m = mi * 16 + ln;
            ap[mi] = *reinterpret_cast<const bf16x8*>(slc + 4096 + ((m * 64 + lg * 16) ^ ((m & 3) << 4)));
        }
        #pragma unroll
        for (int u = 0; u < 2; ++u) {
            int d = u * 16 + ln;
            bv[u] = *reinterpret_cast<const bf16x8*>(slc + ((d * 128 + kkv * 64 + lg * 16) ^ ((d & 7) << 4)));
        }
        #pragma unroll
        for (int mi = 0; mi < 4; ++mi)
            #pragma unroll
            for (int u = 0; u < 2; ++u)
                po[mi][u] = MFMA16(ap[mi], bv[u], po[mi][u]);
    }

    // attn_out bf16 into k/P region (P dead)
    #pragma unroll
    for (int mi = 0; mi < 4; ++mi)
        #pragma unroll
        for (int u = 0; u < 2; ++u)
            #pragma unroll
            for (int r = 0; r < 4; ++r) {
                int t = mi * 16 + lg * 4 + r;
                int d = u * 16 + ln;
                *reinterpret_cast<short*>(slc + 4096 + ((t * 64 + d * 2) ^ ((t & 3) << 4)))
                    = bfr(po[mi][u][r]);
            }
    __syncthreads();   // all waves' attn_out visible

    // ---------- Phase 4: out-proj ----------
    f32x4 fo[4][2];
    #pragma unroll
    for (int mi = 0; mi < 4; ++mi)
        #pragma unroll
        for (int u = 0; u < 2; ++u) fo[mi][u] = (f32x4){0.f,0.f,0.f,0.f};
    float bo0 = bout[wave * 32 + ln];
    float bo1 = bout[wave * 32 + 16 + ln];

    #pragma unroll 1
    for (int hh = 0; hh < 8; ++hh) {
        const char* ahh = lds + hh * 8192 + 4096;
        bf16x8 aa[4];
        #pragma unroll
        for (int mi = 0; mi < 4; ++mi) {
            int t = mi * 16 + ln;
            aa[mi] = *reinterpret_cast<const bf16x8*>(ahh + ((t * 64 + lg * 16) ^ ((t & 3) << 4)));
        }
        bf16x8 bb[2];
        #pragma unroll
        for (int u = 0; u < 2; ++u) {
            if constexpr (USE_WS) {
                bb[u] = *reinterpret_cast<const bf16x8*>(
                    wsb + WS_QKV_BYTES + ((wave * 2 + u) * 8 + hh) * 1024 + fl);
            } else {
                int oc = wave * 32 + u * 16 + ln;
                bb[u] = cvt8(wout + (size_t)oc * 256 + hh * 32 + lg * 8);
            }
        }
        #pragma unroll
        for (int mi = 0; mi < 4; ++mi)
            #pragma unroll
            for (int u = 0; u < 2; ++u)
                fo[mi][u] = MFMA16(aa[mi], bb[u], fo[mi][u]);
    }

    #pragma unroll
    for (int mi = 0; mi < 4; ++mi)
        #pragma unroll
        for (int r = 0; r < 4; ++r) {
            int t = mi * 16 + lg * 4 + r;
            float* op = out + base + (size_t)(((t >> 3) * 128 + (t & 7)) * 256);
            op[wave * 32 + ln]      = fo[mi][0][r] + bo0;
            op[wave * 32 + 16 + ln] = fo[mi][1][r] + bo1;
        }
}

extern "C" void kernel_launch(void* const* d_in, const int* in_sizes, int n_in,
                              void* d_out, int out_size, void* d_ws, size_t ws_size,
                              hipStream_t stream) {
    const float* x    = (const float*)d_in[0];
    const float* wqkv = (const float*)d_in[1];
    const float* peg  = (const float*)d_in[2];
    const float* wout = (const float*)d_in[3];
    const float* bout = (const float*)d_in[4];
    float* out = (float*)d_out;
    if (d_ws != nullptr && ws_size >= WS_TOTAL_BYTES) {
        hipLaunchKernelGGL(prep_kernel, dim3(128), dim3(256), 0, stream,
                           wqkv, wout, (char*)d_ws);
        hipLaunchKernelGGL((winattn_kernel<true>), dim3(2048), dim3(512), 0, stream,
                           x, wqkv, peg, wout, bout, out, (const char*)d_ws);
    } else {
        hipLaunchKernelGGL((winattn_kernel<false>), dim3(2048), dim3(512), 0, stream,
                           x, wqkv, peg, wout, bout, out, nullptr);
    }
}